// Round 7
// baseline (690.186 us; speedup 1.0000x reference)
//
#include <hip/hip_runtime.h>
#include <hip/hip_bf16.h>
#include <stdint.h>

#define CDIV(a, b) (((a) + (b) - 1) / (b))

// ---------------- CSR build ----------------

__global__ __launch_bounds__(256) void count_edges_k(const int* __restrict__ tgt,
                                                     int* __restrict__ cnt, int E) {
    int e = blockIdx.x * 256 + threadIdx.x;
    if (e < E) atomicAdd(&cnt[tgt[e]], 1);
}

__global__ __launch_bounds__(256) void gcnt_k(const int* __restrict__ batch,
                                              int* __restrict__ gcnt, int n) {
    int i = blockIdx.x * 256 + threadIdx.x;
    if (i < n) atomicAdd(&gcnt[batch[i]], 1);
}

// scan1: per-block (1024 elements) exclusive scan -> out, block totals -> bsums
__global__ __launch_bounds__(256) void scan1_k(const int* __restrict__ cnt,
                                               int* __restrict__ out,
                                               int* __restrict__ bsums, int n) {
    __shared__ int sh[256];
    int t = threadIdx.x;
    int base = blockIdx.x * 1024;
    int idx0 = base + t * 4;
    int v[4];
    if (idx0 + 3 < n) {
        int4 vv = *(const int4*)&cnt[idx0];
        v[0] = vv.x; v[1] = vv.y; v[2] = vv.z; v[3] = vv.w;
    } else {
        for (int i = 0; i < 4; ++i) v[i] = (idx0 + i < n) ? cnt[idx0 + i] : 0;
    }
    int s = v[0] + v[1] + v[2] + v[3];
    sh[t] = s;
    __syncthreads();
    for (int off = 1; off < 256; off <<= 1) {
        int x = (t >= off) ? sh[t - off] : 0;
        __syncthreads();
        sh[t] += x;
        __syncthreads();
    }
    int excl = sh[t] - s;
    if (t == 255) bsums[blockIdx.x] = sh[255];
    int run = excl;
    for (int i = 0; i < 4; ++i) {
        if (idx0 + i < n) out[idx0 + i] = run;
        run += v[i];
    }
}

// scan2: single block exclusive scan of block sums (nb <= 128)
__global__ __launch_bounds__(128) void scan2_k(int* __restrict__ bsums, int nb) {
    __shared__ int sh[128];
    int t = threadIdx.x;
    int v = (t < nb) ? bsums[t] : 0;
    sh[t] = v;
    __syncthreads();
    for (int off = 1; off < 128; off <<= 1) {
        int x = (t >= off) ? sh[t - off] : 0;
        __syncthreads();
        sh[t] += x;
        __syncthreads();
    }
    if (t < nb) bsums[t] = sh[t] - v;  // exclusive
}

// scan3: add block offsets -> row_ptr, init cursor, precompute dinv
__global__ __launch_bounds__(256) void scan3_k(int* __restrict__ rowptr,
                                               const int* __restrict__ bsums,
                                               int* __restrict__ cursor,
                                               float* __restrict__ dinv,
                                               const int* __restrict__ cnt,
                                               int n, int etot) {
    int i = blockIdx.x * 256 + threadIdx.x;
    if (i < n) {
        int v = rowptr[i] + bsums[i >> 10];
        rowptr[i] = v;
        cursor[i] = v;
        dinv[i] = rsqrtf((float)cnt[i] + 1.0f);
    }
    if (i == 0) rowptr[n] = etot;
}

__global__ __launch_bounds__(256) void fill_csr_k(const int* __restrict__ ei,
                                                  const int* __restrict__ ea,
                                                  int* __restrict__ cursor,
                                                  unsigned* __restrict__ adj, int E) {
    int e = blockIdx.x * 256 + threadIdx.x;
    if (e < E) {
        int s = ei[e];
        int tg = ei[E + e];
        unsigned a = (unsigned)ea[e];
        int pos = atomicAdd(&cursor[tg], 1);
        adj[pos] = (a << 18) | (unsigned)s;
    }
}

// ---------------- GEMM: Y[n,COUT] = X[n,K] @ W[K,COUT] (+bias) ----------------
template <int K, int COUT, int R>
__global__ __launch_bounds__(256) void gemm_rk(const float* __restrict__ X,
                                               const float* __restrict__ W,
                                               const float* __restrict__ bias,
                                               float* __restrict__ Y, int nrows) {
    constexpr int NCG = COUT / 8;
    constexpr int RG = 256 / NCG;
    constexpr int ROWS = RG * R;
    constexpr int WS = K + 4;
    __shared__ float wt[COUT][WS];
    int t = threadIdx.x;
    for (int i = t; i < K * COUT; i += 256) {
        int k = i / COUT, j = i % COUT;
        wt[j][k] = W[i];
    }
    __syncthreads();
    int cg = t % NCG, g = t / NCG;
    int j0 = cg * 8;
    long rowbase = (long)blockIdx.x * ROWS + (long)g * R;
    float acc[R][8];
#pragma unroll
    for (int r = 0; r < R; ++r)
#pragma unroll
        for (int j = 0; j < 8; ++j) acc[r][j] = 0.0f;

    long rr[R];
#pragma unroll
    for (int r = 0; r < R; ++r) {
        long q = rowbase + r;
        rr[r] = (q < nrows) ? q : (long)(nrows - 1);  // clamp; store guarded
    }
    for (int k0 = 0; k0 < K; k0 += 4) {
        float4 xv[R];
#pragma unroll
        for (int r = 0; r < R; ++r) xv[r] = *(const float4*)(X + rr[r] * K + k0);
        float4 wv[8];
#pragma unroll
        for (int j = 0; j < 8; ++j) wv[j] = *(const float4*)&wt[j0 + j][k0];
#pragma unroll
        for (int r = 0; r < R; ++r)
#pragma unroll
            for (int j = 0; j < 8; ++j) {
                acc[r][j] += xv[r].x * wv[j].x;
                acc[r][j] += xv[r].y * wv[j].y;
                acc[r][j] += xv[r].z * wv[j].z;
                acc[r][j] += xv[r].w * wv[j].w;
            }
    }
#pragma unroll
    for (int r = 0; r < R; ++r) {
        long row = rowbase + r;
        if (row < nrows) {
            float o[8];
#pragma unroll
            for (int j = 0; j < 8; ++j) {
                float v = acc[r][j];
                if (bias) v += bias[j0 + j];
                o[j] = v;
            }
            float4 o0 = make_float4(o[0], o[1], o[2], o[3]);
            float4 o1 = make_float4(o[4], o[5], o[6], o[7]);
            *(float4*)&Y[row * COUT + j0] = o0;
            *(float4*)&Y[row * COUT + j0 + 4] = o1;
        }
    }
}

// ---------------- edge aggregations (gather over CSR) ----------------

__global__ __launch_bounds__(256) void agg_conv_k(const float* __restrict__ xw,
                                                  const unsigned* __restrict__ adj,
                                                  const int* __restrict__ rowptr,
                                                  const float* __restrict__ dinv,
                                                  const int* __restrict__ cnt,
                                                  const float* __restrict__ bias,
                                                  float* __restrict__ out, int n) {
    int t = threadIdx.x;
    int node = blockIdx.x * 8 + (t >> 5);
    int f = t & 31;
    if (node >= n) return;
    int e0 = rowptr[node], e1 = rowptr[node + 1];
    float a0 = 0.0f, a1 = 0.0f;
    int e = e0;
    for (; e + 1 < e1; e += 2) {
        unsigned u0 = adj[e], u1 = adj[e + 1];
        int s0 = u0 & 0x3FFFF, s1 = u1 & 0x3FFFF;
        a0 += dinv[s0] * xw[s0 * 32 + f];
        a1 += dinv[s1] * xw[s1 * 32 + f];
    }
    if (e < e1) {
        unsigned u = adj[e];
        int s = u & 0x3FFFF;
        a0 += dinv[s] * xw[s * 32 + f];
    }
    float degv = (float)cnt[node] + 1.0f;
    float v = dinv[node] * (a0 + a1) + xw[node * 32 + f] * (1.0f / degv) + bias[f];
    out[node * 32 + f] = fmaxf(v, 0.0f);
}

__global__ __launch_bounds__(256) void agg_rs_k(const float* __restrict__ hl,
                                                const unsigned* __restrict__ adj,
                                                const int* __restrict__ rowptr,
                                                const int* __restrict__ cnt,
                                                float* __restrict__ out, int n) {
    int t = threadIdx.x;
    int node = blockIdx.x * 8 + (t >> 5);
    int f = t & 31;
    if (node >= n) return;
    int e0 = rowptr[node], e1 = rowptr[node + 1];
    float a0 = 0.0f, a1 = 0.0f;
    int e = e0;
    for (; e + 1 < e1; e += 2) {
        unsigned u0 = adj[e], u1 = adj[e + 1];
        int s0 = u0 & 0x3FFFF, s1 = u1 & 0x3FFFF;
        int q0 = (u0 >> 18), q1 = (u1 >> 18);
        a0 += hl[s0 * 128 + q0 * 32 + f];
        a1 += hl[s1 * 128 + q1 * 32 + f];
    }
    if (e < e1) {
        unsigned u = adj[e];
        int s = u & 0x3FFFF;
        int q = (u >> 18);
        a0 += hl[s * 128 + q * 32 + f];
    }
    float c = (float)cnt[node];
    out[node * 32 + f] = (a0 + a1) / fmaxf(c, 1.0f);
}

// ---------------- graph pooling (batch sorted: boundary-atomic trick) ----------------

__global__ __launch_bounds__(256) void graph_sum_k(const float* __restrict__ agg,
                                                   const int* __restrict__ batch,
                                                   float* __restrict__ gsum, int n) {
    const int CHUNK = 128;
    int t = threadIdx.x;
    int f = t & 31;
    int j = t >> 5;  // 0..7
    long base = (long)blockIdx.x * (8 * CHUNK) + (long)j * CHUNK;
    if (base >= n) return;
    int end = (int)((n - base < CHUNK) ? (n - base) : CHUNK);
    int cur = batch[base];
    float acc = 0.0f;
    for (int i = 0; i < end; ++i) {
        int b = batch[base + i];
        if (b != cur) {
            atomicAdd(&gsum[cur * 32 + f], acc);
            acc = 0.0f;
            cur = b;
        }
        acc += agg[(base + i) * 32 + f];
    }
    atomicAdd(&gsum[cur * 32 + f], acc);
}

// ---------------- final MLP head ----------------

__global__ __launch_bounds__(256) void mlp_k(const float* __restrict__ gsum,
                                             const int* __restrict__ gcnt,
                                             const float* __restrict__ Wm1,
                                             const float* __restrict__ bm1,
                                             const float* __restrict__ Wm2,
                                             const float* __restrict__ bm2,
                                             float* __restrict__ out, int Gn) {
    __shared__ float w1[1024];
    __shared__ float w2[32];
    __shared__ float b1s[32];
    int t = threadIdx.x;
    for (int i = t; i < 1024; i += 256) w1[i] = Wm1[i];
    if (t < 32) {
        w2[t] = Wm2[t];
        b1s[t] = bm1[t];
    }
    __syncthreads();
    if (t < Gn) {
        float inv = 1.0f / fmaxf((float)gcnt[t], 1.0f);
        float gm[32];
#pragma unroll
        for (int k = 0; k < 32; ++k) gm[k] = gsum[t * 32 + k] * inv;
        float o = bm2[0];
        for (int j = 0; j < 32; ++j) {
            float h = b1s[j];
#pragma unroll
            for (int k = 0; k < 32; ++k) h += gm[k] * w1[k * 32 + j];
            o += fmaxf(h, 0.0f) * w2[j];
        }
        out[t] = 1.0f / (1.0f + expf(-o));
    }
}

// ---------------- launch ----------------

extern "C" void kernel_launch(void* const* d_in, const int* in_sizes, int n_in,
                              void* d_out, int out_size, void* d_ws, size_t ws_size,
                              hipStream_t stream) {
    const float* x = (const float*)d_in[0];
    const int* ei = (const int*)d_in[1];
    const int* ea = (const int*)d_in[2];
    const int* batch = (const int*)d_in[3];
    const float* W1 = (const float*)d_in[4];
    const float* b1 = (const float*)d_in[5];
    const float* W2 = (const float*)d_in[6];
    const float* b2 = (const float*)d_in[7];
    const float* Wl = (const float*)d_in[8];
    const float* bl = (const float*)d_in[9];
    const float* Wm1 = (const float*)d_in[10];
    const float* bm1 = (const float*)d_in[11];
    const float* Wm2 = (const float*)d_in[12];
    const float* bm2 = (const float*)d_in[13];

    const int N = in_sizes[3];
    const int E = in_sizes[2];
    const int Gn = out_size;

    char* ws = (char*)d_ws;
    size_t off = 0;
    auto alloc = [&](size_t bytes) -> void* {
        void* p = ws + off;
        off = (off + bytes + 255) & ~(size_t)255;
        return p;
    };
    int* cnt = (int*)alloc((size_t)N * 4);
    int* rowptr = (int*)alloc((size_t)(N + 1) * 4);
    int* cursor = (int*)alloc((size_t)N * 4);
    float* dinv = (float*)alloc((size_t)N * 4);
    int* bsums = (int*)alloc(512);
    unsigned* adj = (unsigned*)alloc((size_t)E * 4);
    float* gsum = (float*)alloc((size_t)Gn * 32 * 4);
    int* gcnt = (int*)alloc((size_t)Gn * 4);
    float* bufA = (float*)alloc((size_t)N * 32 * 4);
    float* bufB = (float*)alloc((size_t)N * 32 * 4);
    float* hl = (float*)alloc((size_t)N * 128 * 4);

    // Workspace guard: if d_ws is too small, bail out (output stays zero ->
    // absmax ~0.5 signature) instead of corrupting device memory.
    if (off > ws_size) return;

    hipMemsetAsync(cnt, 0, (size_t)N * 4, stream);
    hipMemsetAsync(gsum, 0, (size_t)Gn * 32 * 4 + (size_t)Gn * 4, stream);

    count_edges_k<<<CDIV(E, 256), 256, 0, stream>>>(ei + E, cnt, E);
    gcnt_k<<<CDIV(N, 256), 256, 0, stream>>>(batch, gcnt, N);

    int NB = CDIV(N, 1024);
    scan1_k<<<NB, 256, 0, stream>>>(cnt, rowptr, bsums, N);
    scan2_k<<<1, 128, 0, stream>>>(bsums, NB);
    scan3_k<<<CDIV(N, 256), 256, 0, stream>>>(rowptr, bsums, cursor, dinv, cnt, N, E);
    fill_csr_k<<<CDIV(E, 256), 256, 0, stream>>>(ei, ea, cursor, adj, E);

    // conv1: xw = x @ W1 ; aggregate -> h1 (relu)
    gemm_rk<128, 32, 4><<<CDIV(N, 256), 256, 0, stream>>>(x, W1, nullptr, bufA, N);
    agg_conv_k<<<CDIV(N, 8), 256, 0, stream>>>(bufA, adj, rowptr, dinv, cnt, b1, bufB, N);
    // conv2
    gemm_rk<32, 32, 4><<<CDIV(N, 256), 256, 0, stream>>>(bufB, W2, nullptr, bufA, N);
    agg_conv_k<<<CDIV(N, 8), 256, 0, stream>>>(bufA, adj, rowptr, dinv, cnt, b2, bufB, N);
    // hl = h2 @ Wl + bl
    gemm_rk<32, 128, 4><<<CDIV(N, 64), 256, 0, stream>>>(bufB, Wl, bl, hl, N);
    // rs aggregation (mean by cnt)
    agg_rs_k<<<CDIV(N, 8), 256, 0, stream>>>(hl, adj, rowptr, cnt, bufA, N);
    // graph mean + head
    graph_sum_k<<<CDIV(N, 1024), 256, 0, stream>>>(bufA, batch, gsum, N);
    mlp_k<<<1, 256, 0, stream>>>(gsum, gcnt, Wm1, bm1, Wm2, bm2, (float*)d_out, Gn);
}

// Round 8
// 551.377 us; speedup vs baseline: 1.2518x; 1.2518x over previous
//
#include <hip/hip_runtime.h>
#include <hip/hip_bf16.h>
#include <stdint.h>

#define CDIV(a, b) (((a) + (b) - 1) / (b))

// ---------------- CSR build ----------------

__global__ __launch_bounds__(256) void count_edges_k(const int* __restrict__ tgt,
                                                     int* __restrict__ cnt, int E) {
    int e = blockIdx.x * 256 + threadIdx.x;
    if (e < E) atomicAdd(&cnt[tgt[e]], 1);
}

// batch is sorted: gcnt[g] = lower_bound(g+1) - lower_bound(g). No atomics.
__device__ __forceinline__ int lb_sorted(const int* __restrict__ b, int n, int g) {
    int lo = 0, hi = n;
    while (lo < hi) {
        int m = (lo + hi) >> 1;
        if (b[m] < g) lo = m + 1; else hi = m;
    }
    return lo;
}

__global__ __launch_bounds__(256) void gbounds_k(const int* __restrict__ batch,
                                                 int* __restrict__ gcnt, int n, int Gn) {
    int g = blockIdx.x * 256 + threadIdx.x;
    if (g < Gn) {
        int a = lb_sorted(batch, n, g);
        int b2 = lb_sorted(batch, n, g + 1);
        gcnt[g] = b2 - a;
    }
}

// scan1: per-block (1024 elements) exclusive scan -> out, block totals -> bsums
__global__ __launch_bounds__(256) void scan1_k(const int* __restrict__ cnt,
                                               int* __restrict__ out,
                                               int* __restrict__ bsums, int n) {
    __shared__ int sh[256];
    int t = threadIdx.x;
    int base = blockIdx.x * 1024;
    int idx0 = base + t * 4;
    int v[4];
    if (idx0 + 3 < n) {
        int4 vv = *(const int4*)&cnt[idx0];
        v[0] = vv.x; v[1] = vv.y; v[2] = vv.z; v[3] = vv.w;
    } else {
        for (int i = 0; i < 4; ++i) v[i] = (idx0 + i < n) ? cnt[idx0 + i] : 0;
    }
    int s = v[0] + v[1] + v[2] + v[3];
    sh[t] = s;
    __syncthreads();
    for (int off = 1; off < 256; off <<= 1) {
        int x = (t >= off) ? sh[t - off] : 0;
        __syncthreads();
        sh[t] += x;
        __syncthreads();
    }
    int excl = sh[t] - s;
    if (t == 255) bsums[blockIdx.x] = sh[255];
    int run = excl;
    for (int i = 0; i < 4; ++i) {
        if (idx0 + i < n) out[idx0 + i] = run;
        run += v[i];
    }
}

// scan2: single block exclusive scan of block sums (nb <= 128)
__global__ __launch_bounds__(128) void scan2_k(int* __restrict__ bsums, int nb) {
    __shared__ int sh[128];
    int t = threadIdx.x;
    int v = (t < nb) ? bsums[t] : 0;
    sh[t] = v;
    __syncthreads();
    for (int off = 1; off < 128; off <<= 1) {
        int x = (t >= off) ? sh[t - off] : 0;
        __syncthreads();
        sh[t] += x;
        __syncthreads();
    }
    if (t < nb) bsums[t] = sh[t] - v;  // exclusive
}

// scan3: add block offsets -> row_ptr, init cursor, precompute dinv
__global__ __launch_bounds__(256) void scan3_k(int* __restrict__ rowptr,
                                               const int* __restrict__ bsums,
                                               int* __restrict__ cursor,
                                               float* __restrict__ dinv,
                                               const int* __restrict__ cnt,
                                               int n, int etot) {
    int i = blockIdx.x * 256 + threadIdx.x;
    if (i < n) {
        int v = rowptr[i] + bsums[i >> 10];
        rowptr[i] = v;
        cursor[i] = v;
        dinv[i] = rsqrtf((float)cnt[i] + 1.0f);
    }
    if (i == 0) rowptr[n] = etot;
}

__global__ __launch_bounds__(256) void fill_csr_k(const int* __restrict__ ei,
                                                  const int* __restrict__ ea,
                                                  int* __restrict__ cursor,
                                                  unsigned* __restrict__ adj, int E) {
    int e = blockIdx.x * 256 + threadIdx.x;
    if (e < E) {
        int s = ei[e];
        int tg = ei[E + e];
        unsigned a = (unsigned)ea[e];
        int pos = atomicAdd(&cursor[tg], 1);
        adj[pos] = (a << 18) | (unsigned)s;
    }
}

// ---------------- GEMM: Y[n,COUT] = X[n,K] @ W[K,COUT] (+bias) ----------------
template <int K, int COUT, int R>
__global__ __launch_bounds__(256) void gemm_rk(const float* __restrict__ X,
                                               const float* __restrict__ W,
                                               const float* __restrict__ bias,
                                               float* __restrict__ Y, int nrows) {
    constexpr int NCG = COUT / 8;
    constexpr int RG = 256 / NCG;
    constexpr int ROWS = RG * R;
    constexpr int WS = K + 4;
    __shared__ float wt[COUT][WS];
    int t = threadIdx.x;
    for (int i = t; i < K * COUT; i += 256) {
        int k = i / COUT, j = i % COUT;
        wt[j][k] = W[i];
    }
    __syncthreads();
    int cg = t % NCG, g = t / NCG;
    int j0 = cg * 8;
    long rowbase = (long)blockIdx.x * ROWS + (long)g * R;
    float acc[R][8];
#pragma unroll
    for (int r = 0; r < R; ++r)
#pragma unroll
        for (int j = 0; j < 8; ++j) acc[r][j] = 0.0f;

    long rr[R];
#pragma unroll
    for (int r = 0; r < R; ++r) {
        long q = rowbase + r;
        rr[r] = (q < nrows) ? q : (long)(nrows - 1);  // clamp; store guarded
    }
    for (int k0 = 0; k0 < K; k0 += 4) {
        float4 xv[R];
#pragma unroll
        for (int r = 0; r < R; ++r) xv[r] = *(const float4*)(X + rr[r] * K + k0);
        float4 wv[8];
#pragma unroll
        for (int j = 0; j < 8; ++j) wv[j] = *(const float4*)&wt[j0 + j][k0];
#pragma unroll
        for (int r = 0; r < R; ++r)
#pragma unroll
            for (int j = 0; j < 8; ++j) {
                acc[r][j] += xv[r].x * wv[j].x;
                acc[r][j] += xv[r].y * wv[j].y;
                acc[r][j] += xv[r].z * wv[j].z;
                acc[r][j] += xv[r].w * wv[j].w;
            }
    }
#pragma unroll
    for (int r = 0; r < R; ++r) {
        long row = rowbase + r;
        if (row < nrows) {
            float o[8];
#pragma unroll
            for (int j = 0; j < 8; ++j) {
                float v = acc[r][j];
                if (bias) v += bias[j0 + j];
                o[j] = v;
            }
            float4 o0 = make_float4(o[0], o[1], o[2], o[3]);
            float4 o1 = make_float4(o[4], o[5], o[6], o[7]);
            *(float4*)&Y[row * COUT + j0] = o0;
            *(float4*)&Y[row * COUT + j0 + 4] = o1;
        }
    }
}

// ---------------- edge aggregations (gather over CSR) ----------------

__global__ __launch_bounds__(256) void agg_conv_k(const float* __restrict__ xw,
                                                  const unsigned* __restrict__ adj,
                                                  const int* __restrict__ rowptr,
                                                  const float* __restrict__ dinv,
                                                  const int* __restrict__ cnt,
                                                  const float* __restrict__ bias,
                                                  float* __restrict__ out, int n) {
    int t = threadIdx.x;
    int node = blockIdx.x * 8 + (t >> 5);
    int f = t & 31;
    if (node >= n) return;
    int e0 = rowptr[node], e1 = rowptr[node + 1];
    float a0 = 0.0f, a1 = 0.0f;
    int e = e0;
    for (; e + 1 < e1; e += 2) {
        unsigned u0 = adj[e], u1 = adj[e + 1];
        int s0 = u0 & 0x3FFFF, s1 = u1 & 0x3FFFF;
        a0 += dinv[s0] * xw[s0 * 32 + f];
        a1 += dinv[s1] * xw[s1 * 32 + f];
    }
    if (e < e1) {
        unsigned u = adj[e];
        int s = u & 0x3FFFF;
        a0 += dinv[s] * xw[s * 32 + f];
    }
    float degv = (float)cnt[node] + 1.0f;
    float v = dinv[node] * (a0 + a1) + xw[node * 32 + f] * (1.0f / degv) + bias[f];
    out[node * 32 + f] = fmaxf(v, 0.0f);
}

__global__ __launch_bounds__(256) void agg_rs_k(const float* __restrict__ hl,
                                                const unsigned* __restrict__ adj,
                                                const int* __restrict__ rowptr,
                                                const int* __restrict__ cnt,
                                                float* __restrict__ out, int n) {
    int t = threadIdx.x;
    int node = blockIdx.x * 8 + (t >> 5);
    int f = t & 31;
    if (node >= n) return;
    int e0 = rowptr[node], e1 = rowptr[node + 1];
    float a0 = 0.0f, a1 = 0.0f;
    int e = e0;
    for (; e + 1 < e1; e += 2) {
        unsigned u0 = adj[e], u1 = adj[e + 1];
        int s0 = u0 & 0x3FFFF, s1 = u1 & 0x3FFFF;
        int q0 = (u0 >> 18), q1 = (u1 >> 18);
        a0 += hl[s0 * 128 + q0 * 32 + f];
        a1 += hl[s1 * 128 + q1 * 32 + f];
    }
    if (e < e1) {
        unsigned u = adj[e];
        int s = u & 0x3FFFF;
        int q = (u >> 18);
        a0 += hl[s * 128 + q * 32 + f];
    }
    float c = (float)cnt[node];
    out[node * 32 + f] = (a0 + a1) / fmaxf(c, 1.0f);
}

// ---------------- graph pooling (batch sorted: boundary-atomic trick) ----------------

__global__ __launch_bounds__(256) void graph_sum_k(const float* __restrict__ agg,
                                                   const int* __restrict__ batch,
                                                   float* __restrict__ gsum, int n) {
    const int CHUNK = 128;
    int t = threadIdx.x;
    int f = t & 31;
    int j = t >> 5;  // 0..7
    long base = (long)blockIdx.x * (8 * CHUNK) + (long)j * CHUNK;
    if (base >= n) return;
    int end = (int)((n - base < CHUNK) ? (n - base) : CHUNK);
    int cur = batch[base];
    float acc = 0.0f;
    for (int i = 0; i < end; ++i) {
        int b = batch[base + i];
        if (b != cur) {
            atomicAdd(&gsum[cur * 32 + f], acc);
            acc = 0.0f;
            cur = b;
        }
        acc += agg[(base + i) * 32 + f];
    }
    atomicAdd(&gsum[cur * 32 + f], acc);
}

// ---------------- final MLP head ----------------

__global__ __launch_bounds__(256) void mlp_k(const float* __restrict__ gsum,
                                             const int* __restrict__ gcnt,
                                             const float* __restrict__ Wm1,
                                             const float* __restrict__ bm1,
                                             const float* __restrict__ Wm2,
                                             const float* __restrict__ bm2,
                                             float* __restrict__ out, int Gn) {
    __shared__ float w1[1024];
    __shared__ float w2[32];
    __shared__ float b1s[32];
    int t = threadIdx.x;
    for (int i = t; i < 1024; i += 256) w1[i] = Wm1[i];
    if (t < 32) {
        w2[t] = Wm2[t];
        b1s[t] = bm1[t];
    }
    __syncthreads();
    if (t < Gn) {
        float inv = 1.0f / fmaxf((float)gcnt[t], 1.0f);
        float gm[32];
#pragma unroll
        for (int k = 0; k < 32; ++k) gm[k] = gsum[t * 32 + k] * inv;
        float o = bm2[0];
        for (int j = 0; j < 32; ++j) {
            float h = b1s[j];
#pragma unroll
            for (int k = 0; k < 32; ++k) h += gm[k] * w1[k * 32 + j];
            o += fmaxf(h, 0.0f) * w2[j];
        }
        out[t] = 1.0f / (1.0f + expf(-o));
    }
}

// ---------------- launch ----------------

extern "C" void kernel_launch(void* const* d_in, const int* in_sizes, int n_in,
                              void* d_out, int out_size, void* d_ws, size_t ws_size,
                              hipStream_t stream) {
    const float* x = (const float*)d_in[0];
    const int* ei = (const int*)d_in[1];
    const int* ea = (const int*)d_in[2];
    const int* batch = (const int*)d_in[3];
    const float* W1 = (const float*)d_in[4];
    const float* b1 = (const float*)d_in[5];
    const float* W2 = (const float*)d_in[6];
    const float* b2 = (const float*)d_in[7];
    const float* Wl = (const float*)d_in[8];
    const float* bl = (const float*)d_in[9];
    const float* Wm1 = (const float*)d_in[10];
    const float* bm1 = (const float*)d_in[11];
    const float* Wm2 = (const float*)d_in[12];
    const float* bm2 = (const float*)d_in[13];

    const int N = in_sizes[3];
    const int E = in_sizes[2];
    const int Gn = out_size;

    char* ws = (char*)d_ws;
    size_t off = 0;
    auto alloc = [&](size_t bytes) -> void* {
        void* p = ws + off;
        off = (off + bytes + 255) & ~(size_t)255;
        return p;
    };
    int* cnt = (int*)alloc((size_t)N * 4);
    int* rowptr = (int*)alloc((size_t)(N + 1) * 4);
    int* cursor = (int*)alloc((size_t)N * 4);
    float* dinv = (float*)alloc((size_t)N * 4);
    int* bsums = (int*)alloc(512);
    unsigned* adj = (unsigned*)alloc((size_t)E * 4);
    float* gsum = (float*)alloc((size_t)Gn * 32 * 4);
    int* gcnt = (int*)alloc((size_t)Gn * 4);
    float* bufA = (float*)alloc((size_t)N * 32 * 4);
    float* bufB = (float*)alloc((size_t)N * 32 * 4);
    float* hl = (float*)alloc((size_t)N * 128 * 4);

    // Workspace guard: if d_ws is too small, bail out (output stays zero ->
    // absmax ~0.5 signature) instead of corrupting device memory.
    if (off > ws_size) return;

    hipMemsetAsync(cnt, 0, (size_t)N * 4, stream);
    hipMemsetAsync(gsum, 0, (size_t)Gn * 32 * 4, stream);

    count_edges_k<<<CDIV(E, 256), 256, 0, stream>>>(ei + E, cnt, E);
    gbounds_k<<<CDIV(Gn, 256), 256, 0, stream>>>(batch, gcnt, N, Gn);

    int NB = CDIV(N, 1024);
    scan1_k<<<NB, 256, 0, stream>>>(cnt, rowptr, bsums, N);
    scan2_k<<<1, 128, 0, stream>>>(bsums, NB);
    scan3_k<<<CDIV(N, 256), 256, 0, stream>>>(rowptr, bsums, cursor, dinv, cnt, N, E);
    fill_csr_k<<<CDIV(E, 256), 256, 0, stream>>>(ei, ea, cursor, adj, E);

    // conv1: xw = x @ W1 ; aggregate -> h1 (relu)
    gemm_rk<128, 32, 4><<<CDIV(N, 256), 256, 0, stream>>>(x, W1, nullptr, bufA, N);
    agg_conv_k<<<CDIV(N, 8), 256, 0, stream>>>(bufA, adj, rowptr, dinv, cnt, b1, bufB, N);
    // conv2
    gemm_rk<32, 32, 4><<<CDIV(N, 256), 256, 0, stream>>>(bufB, W2, nullptr, bufA, N);
    agg_conv_k<<<CDIV(N, 8), 256, 0, stream>>>(bufA, adj, rowptr, dinv, cnt, b2, bufB, N);
    // hl = h2 @ Wl + bl
    gemm_rk<32, 128, 4><<<CDIV(N, 64), 256, 0, stream>>>(bufB, Wl, bl, hl, N);
    // rs aggregation (mean by cnt)
    agg_rs_k<<<CDIV(N, 8), 256, 0, stream>>>(hl, adj, rowptr, cnt, bufA, N);
    // graph mean + head
    graph_sum_k<<<CDIV(N, 1024), 256, 0, stream>>>(bufA, batch, gsum, N);
    mlp_k<<<1, 256, 0, stream>>>(gsum, gcnt, Wm1, bm1, Wm2, bm2, (float*)d_out, Gn);
}

// Round 9
// 426.289 us; speedup vs baseline: 1.6191x; 1.2934x over previous
//
#include <hip/hip_runtime.h>
#include <hip/hip_bf16.h>
#include <stdint.h>

#define CDIV(a, b) (((a) + (b) - 1) / (b))

// Bucketed CSR build: bucket = tgt >> BSH (512 nodes / bucket).
// Supports N <= 512*512 = 262144 (N=100000 here -> 196 buckets).
constexpr int BSH = 9;
#define TILE_A 2048

// ---- coarse histogram over buckets ----
__global__ __launch_bounds__(256) void coarse_hist_k(const int* __restrict__ tgt,
                                                     int* __restrict__ bcnt, int E, int nb) {
    __shared__ int h[512];
    int t = threadIdx.x;
    for (int i = t; i < nb; i += 256) h[i] = 0;
    __syncthreads();
    for (int e = blockIdx.x * 256 + t; e < E; e += gridDim.x * 256)
        atomicAdd(&h[tgt[e] >> BSH], 1);
    __syncthreads();
    for (int i = t; i < nb; i += 256)
        if (h[i]) atomicAdd(&bcnt[i], h[i]);
}

// ---- exclusive scan of bucket counts (single block, nb <= 512) ----
__global__ __launch_bounds__(256) void bucket_scan_k(const int* __restrict__ bcnt,
                                                     int* __restrict__ bbase,
                                                     int* __restrict__ bcur, int nb, int E) {
    __shared__ int sp[256];
    int t = threadIdx.x;
    int c0 = (2 * t < nb) ? bcnt[2 * t] : 0;
    int c1 = (2 * t + 1 < nb) ? bcnt[2 * t + 1] : 0;
    int s2 = c0 + c1;
    sp[t] = s2;
    __syncthreads();
    for (int off = 1; off < 256; off <<= 1) {
        int x = (t >= off) ? sp[t - off] : 0;
        __syncthreads();
        sp[t] += x;
        __syncthreads();
    }
    int excl = sp[t] - s2;
    if (2 * t < nb) { bbase[2 * t] = excl; bcur[2 * t] = excl; }
    if (2 * t + 1 < nb) { bbase[2 * t + 1] = excl + c0; bcur[2 * t + 1] = excl + c0; }
    if (t == 0) bbase[nb] = E;
}

// ---- phase A: bin edges into bucket-major tmp[] with coalesced run writes ----
__global__ __launch_bounds__(256) void binA_k(const int* __restrict__ ei,
                                              const int* __restrict__ ea,
                                              int* __restrict__ bcur,
                                              unsigned long long* __restrict__ tmp, int E) {
    __shared__ unsigned long long stage[TILE_A];  // 16 KB
    __shared__ int h_cnt[512], h_excl[512], h_cur[512], h_run[512], sp[256];
    int t = threadIdx.x;
    int base = blockIdx.x * TILE_A;
    int nt = min(TILE_A, E - base);
    for (int i = t; i < 512; i += 256) { h_cnt[i] = 0; h_cur[i] = 0; }
    __syncthreads();
    unsigned long long pk[8];
    int bk[8];
#pragma unroll
    for (int k = 0; k < 8; ++k) {
        int e = base + t + k * 256;
        bk[k] = -1;
        if (e < E) {
            int s = ei[e], tg = ei[E + e];
            unsigned a = (unsigned)ea[e];
            pk[k] = ((unsigned long long)(unsigned)tg << 20) |
                    ((unsigned long long)a << 18) | (unsigned long long)(unsigned)s;
            bk[k] = tg >> BSH;
            atomicAdd(&h_cnt[bk[k]], 1);
        }
    }
    __syncthreads();
    // scan 512 counts (thread t owns 2t, 2t+1)
    int c0 = h_cnt[2 * t], c1 = h_cnt[2 * t + 1];
    int s2 = c0 + c1;
    sp[t] = s2;
    __syncthreads();
    for (int off = 1; off < 256; off <<= 1) {
        int x = (t >= off) ? sp[t - off] : 0;
        __syncthreads();
        sp[t] += x;
        __syncthreads();
    }
    int excl = sp[t] - s2;
    h_excl[2 * t] = excl;
    h_excl[2 * t + 1] = excl + c0;
    __syncthreads();
    // reserve global runs: one atomic per (block,bucket)
    for (int i = t; i < 512; i += 256)
        if (h_cnt[i]) h_run[i] = atomicAdd(&bcur[i], h_cnt[i]);
    // reorder into bucket-grouped LDS staging
#pragma unroll
    for (int k = 0; k < 8; ++k) {
        if (bk[k] >= 0) {
            int r = atomicAdd(&h_cur[bk[k]], 1);
            stage[h_excl[bk[k]] + r] = pk[k];
        }
    }
    __syncthreads();
    // coalesced write-out of runs
    for (int i = t; i < nt; i += 256) {
        unsigned long long v = stage[i];
        int b = (int)(v >> 20) >> BSH;
        tmp[h_run[b] + (i - h_excl[b])] = v;
    }
}

// ---- phase B: per-bucket node hist -> rowptr/cnt/dinv, then local scatter to adj ----
__global__ __launch_bounds__(256) void binB_k(const unsigned long long* __restrict__ tmp,
                                              const int* __restrict__ bbase,
                                              unsigned* __restrict__ adj,
                                              int* __restrict__ rowptr,
                                              int* __restrict__ cnt,
                                              float* __restrict__ dinv, int N, int E) {
    __shared__ int ncnt[512], nbase[512], ncur[512], sp[256];
    int t = threadIdx.x, b = blockIdx.x;
    int e0 = bbase[b], e1 = bbase[b + 1];
    int node0 = b << BSH;
    int nn = min(512, N - node0);
    for (int i = t; i < 512; i += 256) { ncnt[i] = 0; ncur[i] = 0; }
    __syncthreads();
    for (int e = e0 + t; e < e1; e += 256) {
        int li = (int)(tmp[e] >> 20) - node0;
        atomicAdd(&ncnt[li], 1);
    }
    __syncthreads();
    int c0 = ncnt[2 * t], c1 = ncnt[2 * t + 1];
    int s2 = c0 + c1;
    sp[t] = s2;
    __syncthreads();
    for (int off = 1; off < 256; off <<= 1) {
        int x = (t >= off) ? sp[t - off] : 0;
        __syncthreads();
        sp[t] += x;
        __syncthreads();
    }
    int excl = sp[t] - s2;
    nbase[2 * t] = excl;
    nbase[2 * t + 1] = excl + c0;
    __syncthreads();
    for (int i = t; i < nn; i += 256) {
        int node = node0 + i;
        rowptr[node] = e0 + nbase[i];
        int c = ncnt[i];
        cnt[node] = c;
        dinv[node] = rsqrtf((float)c + 1.0f);
    }
    if (b == 0 && t == 0) rowptr[N] = E;
    for (int e = e0 + t; e < e1; e += 256) {
        unsigned long long v = tmp[e];
        int li = (int)(v >> 20) - node0;
        int r = atomicAdd(&ncur[li], 1);
        adj[e0 + nbase[li] + r] = (unsigned)(v & 0xFFFFFull);
    }
}

// batch is sorted: gcnt[g] = lower_bound(g+1) - lower_bound(g). No atomics.
__device__ __forceinline__ int lb_sorted(const int* __restrict__ b, int n, int g) {
    int lo = 0, hi = n;
    while (lo < hi) {
        int m = (lo + hi) >> 1;
        if (b[m] < g) lo = m + 1; else hi = m;
    }
    return lo;
}

__global__ __launch_bounds__(256) void gbounds_k(const int* __restrict__ batch,
                                                 int* __restrict__ gcnt, int n, int Gn) {
    int g = blockIdx.x * 256 + threadIdx.x;
    if (g < Gn) {
        int a = lb_sorted(batch, n, g);
        int b2 = lb_sorted(batch, n, g + 1);
        gcnt[g] = b2 - a;
    }
}

// ---------------- GEMM: Y[n,COUT] = X[n,K] @ W[K,COUT] (+bias) ----------------
template <int K, int COUT, int R>
__global__ __launch_bounds__(256) void gemm_rk(const float* __restrict__ X,
                                               const float* __restrict__ W,
                                               const float* __restrict__ bias,
                                               float* __restrict__ Y, int nrows) {
    constexpr int NCG = COUT / 8;
    constexpr int RG = 256 / NCG;
    constexpr int ROWS = RG * R;
    constexpr int WS = K + 4;
    __shared__ float wt[COUT][WS];
    int t = threadIdx.x;
    for (int i = t; i < K * COUT; i += 256) {
        int k = i / COUT, j = i % COUT;
        wt[j][k] = W[i];
    }
    __syncthreads();
    int cg = t % NCG, g = t / NCG;
    int j0 = cg * 8;
    long rowbase = (long)blockIdx.x * ROWS + (long)g * R;
    float acc[R][8];
#pragma unroll
    for (int r = 0; r < R; ++r)
#pragma unroll
        for (int j = 0; j < 8; ++j) acc[r][j] = 0.0f;

    long rr[R];
#pragma unroll
    for (int r = 0; r < R; ++r) {
        long q = rowbase + r;
        rr[r] = (q < nrows) ? q : (long)(nrows - 1);  // clamp; store guarded
    }
    for (int k0 = 0; k0 < K; k0 += 4) {
        float4 xv[R];
#pragma unroll
        for (int r = 0; r < R; ++r) xv[r] = *(const float4*)(X + rr[r] * K + k0);
        float4 wv[8];
#pragma unroll
        for (int j = 0; j < 8; ++j) wv[j] = *(const float4*)&wt[j0 + j][k0];
#pragma unroll
        for (int r = 0; r < R; ++r)
#pragma unroll
            for (int j = 0; j < 8; ++j) {
                acc[r][j] += xv[r].x * wv[j].x;
                acc[r][j] += xv[r].y * wv[j].y;
                acc[r][j] += xv[r].z * wv[j].z;
                acc[r][j] += xv[r].w * wv[j].w;
            }
    }
#pragma unroll
    for (int r = 0; r < R; ++r) {
        long row = rowbase + r;
        if (row < nrows) {
            float o[8];
#pragma unroll
            for (int j = 0; j < 8; ++j) {
                float v = acc[r][j];
                if (bias) v += bias[j0 + j];
                o[j] = v;
            }
            float4 o0 = make_float4(o[0], o[1], o[2], o[3]);
            float4 o1 = make_float4(o[4], o[5], o[6], o[7]);
            *(float4*)&Y[row * COUT + j0] = o0;
            *(float4*)&Y[row * COUT + j0 + 4] = o1;
        }
    }
}

// ---------------- edge aggregations (gather over CSR) ----------------

__global__ __launch_bounds__(256) void agg_conv_k(const float* __restrict__ xw,
                                                  const unsigned* __restrict__ adj,
                                                  const int* __restrict__ rowptr,
                                                  const float* __restrict__ dinv,
                                                  const int* __restrict__ cnt,
                                                  const float* __restrict__ bias,
                                                  float* __restrict__ out, int n) {
    int t = threadIdx.x;
    int node = blockIdx.x * 8 + (t >> 5);
    int f = t & 31;
    if (node >= n) return;
    int e0 = rowptr[node], e1 = rowptr[node + 1];
    float a0 = 0.0f, a1 = 0.0f;
    int e = e0;
    for (; e + 1 < e1; e += 2) {
        unsigned u0 = adj[e], u1 = adj[e + 1];
        int s0 = u0 & 0x3FFFF, s1 = u1 & 0x3FFFF;
        a0 += dinv[s0] * xw[s0 * 32 + f];
        a1 += dinv[s1] * xw[s1 * 32 + f];
    }
    if (e < e1) {
        unsigned u = adj[e];
        int s = u & 0x3FFFF;
        a0 += dinv[s] * xw[s * 32 + f];
    }
    float degv = (float)cnt[node] + 1.0f;
    float v = dinv[node] * (a0 + a1) + xw[node * 32 + f] * (1.0f / degv) + bias[f];
    out[node * 32 + f] = fmaxf(v, 0.0f);
}

__global__ __launch_bounds__(256) void agg_rs_k(const float* __restrict__ hl,
                                                const unsigned* __restrict__ adj,
                                                const int* __restrict__ rowptr,
                                                const int* __restrict__ cnt,
                                                float* __restrict__ out, int n) {
    int t = threadIdx.x;
    int node = blockIdx.x * 8 + (t >> 5);
    int f = t & 31;
    if (node >= n) return;
    int e0 = rowptr[node], e1 = rowptr[node + 1];
    float a0 = 0.0f, a1 = 0.0f;
    int e = e0;
    for (; e + 1 < e1; e += 2) {
        unsigned u0 = adj[e], u1 = adj[e + 1];
        int s0 = u0 & 0x3FFFF, s1 = u1 & 0x3FFFF;
        int q0 = (u0 >> 18), q1 = (u1 >> 18);
        a0 += hl[s0 * 128 + q0 * 32 + f];
        a1 += hl[s1 * 128 + q1 * 32 + f];
    }
    if (e < e1) {
        unsigned u = adj[e];
        int s = u & 0x3FFFF;
        int q = (u >> 18);
        a0 += hl[s * 128 + q * 32 + f];
    }
    float c = (float)cnt[node];
    out[node * 32 + f] = (a0 + a1) / fmaxf(c, 1.0f);
}

// ---------------- graph pooling (batch sorted: boundary-atomic trick) ----------------

__global__ __launch_bounds__(256) void graph_sum_k(const float* __restrict__ agg,
                                                   const int* __restrict__ batch,
                                                   float* __restrict__ gsum, int n) {
    const int CHUNK = 128;
    int t = threadIdx.x;
    int f = t & 31;
    int j = t >> 5;  // 0..7
    long base = (long)blockIdx.x * (8 * CHUNK) + (long)j * CHUNK;
    if (base >= n) return;
    int end = (int)((n - base < CHUNK) ? (n - base) : CHUNK);
    int cur = batch[base];
    float acc = 0.0f;
    for (int i = 0; i < end; ++i) {
        int b = batch[base + i];
        if (b != cur) {
            atomicAdd(&gsum[cur * 32 + f], acc);
            acc = 0.0f;
            cur = b;
        }
        acc += agg[(base + i) * 32 + f];
    }
    atomicAdd(&gsum[cur * 32 + f], acc);
}

// ---------------- final MLP head ----------------

__global__ __launch_bounds__(256) void mlp_k(const float* __restrict__ gsum,
                                             const int* __restrict__ gcnt,
                                             const float* __restrict__ Wm1,
                                             const float* __restrict__ bm1,
                                             const float* __restrict__ Wm2,
                                             const float* __restrict__ bm2,
                                             float* __restrict__ out, int Gn) {
    __shared__ float w1[1024];
    __shared__ float w2[32];
    __shared__ float b1s[32];
    int t = threadIdx.x;
    for (int i = t; i < 1024; i += 256) w1[i] = Wm1[i];
    if (t < 32) {
        w2[t] = Wm2[t];
        b1s[t] = bm1[t];
    }
    __syncthreads();
    if (t < Gn) {
        float inv = 1.0f / fmaxf((float)gcnt[t], 1.0f);
        float gm[32];
#pragma unroll
        for (int k = 0; k < 32; ++k) gm[k] = gsum[t * 32 + k] * inv;
        float o = bm2[0];
        for (int j = 0; j < 32; ++j) {
            float h = b1s[j];
#pragma unroll
            for (int k = 0; k < 32; ++k) h += gm[k] * w1[k * 32 + j];
            o += fmaxf(h, 0.0f) * w2[j];
        }
        out[t] = 1.0f / (1.0f + expf(-o));
    }
}

// ---------------- launch ----------------

extern "C" void kernel_launch(void* const* d_in, const int* in_sizes, int n_in,
                              void* d_out, int out_size, void* d_ws, size_t ws_size,
                              hipStream_t stream) {
    const float* x = (const float*)d_in[0];
    const int* ei = (const int*)d_in[1];
    const int* ea = (const int*)d_in[2];
    const int* batch = (const int*)d_in[3];
    const float* W1 = (const float*)d_in[4];
    const float* b1 = (const float*)d_in[5];
    const float* W2 = (const float*)d_in[6];
    const float* b2 = (const float*)d_in[7];
    const float* Wl = (const float*)d_in[8];
    const float* bl = (const float*)d_in[9];
    const float* Wm1 = (const float*)d_in[10];
    const float* bm1 = (const float*)d_in[11];
    const float* Wm2 = (const float*)d_in[12];
    const float* bm2 = (const float*)d_in[13];

    const int N = in_sizes[3];
    const int E = in_sizes[2];
    const int Gn = out_size;
    const int NBUCKET = CDIV(N, 512);

    char* ws = (char*)d_ws;
    size_t off = 0;
    auto alloc = [&](size_t bytes) -> void* {
        void* p = ws + off;
        off = (off + bytes + 255) & ~(size_t)255;
        return p;
    };
    int* cnt = (int*)alloc((size_t)N * 4);
    int* rowptr = (int*)alloc((size_t)(N + 1) * 4);
    float* dinv = (float*)alloc((size_t)N * 4);
    int* bcnt = (int*)alloc(512 * 4);
    int* bbase = (int*)alloc(513 * 4);
    int* bcur = (int*)alloc(512 * 4);
    unsigned* adj = (unsigned*)alloc((size_t)E * 4);
    float* gsum = (float*)alloc((size_t)Gn * 32 * 4);
    int* gcnt = (int*)alloc((size_t)Gn * 4);
    float* bufA = (float*)alloc((size_t)N * 32 * 4);
    float* bufB = (float*)alloc((size_t)N * 32 * 4);
    float* hl = (float*)alloc((size_t)N * 128 * 4);
    // tmp (E u64 = 12.8 MB) aliases hl (51.2 MB): CSR build finishes before hl is written.
    unsigned long long* tmp = (unsigned long long*)hl;

    // Workspace / bucket-capacity guard (output stays zero -> absmax ~0.5 signature).
    if (off > ws_size || NBUCKET > 512) return;

    hipMemsetAsync(bcnt, 0, 512 * 4, stream);
    hipMemsetAsync(gsum, 0, (size_t)Gn * 32 * 4, stream);

    coarse_hist_k<<<400, 256, 0, stream>>>(ei + E, bcnt, E, NBUCKET);
    bucket_scan_k<<<1, 256, 0, stream>>>(bcnt, bbase, bcur, NBUCKET, E);
    binA_k<<<CDIV(E, TILE_A), 256, 0, stream>>>(ei, ea, bcur, tmp, E);
    binB_k<<<NBUCKET, 256, 0, stream>>>(tmp, bbase, adj, rowptr, cnt, dinv, N, E);
    gbounds_k<<<CDIV(Gn, 256), 256, 0, stream>>>(batch, gcnt, N, Gn);

    // conv1: xw = x @ W1 ; aggregate -> h1 (relu)
    gemm_rk<128, 32, 4><<<CDIV(N, 256), 256, 0, stream>>>(x, W1, nullptr, bufA, N);
    agg_conv_k<<<CDIV(N, 8), 256, 0, stream>>>(bufA, adj, rowptr, dinv, cnt, b1, bufB, N);
    // conv2
    gemm_rk<32, 32, 4><<<CDIV(N, 256), 256, 0, stream>>>(bufB, W2, nullptr, bufA, N);
    agg_conv_k<<<CDIV(N, 8), 256, 0, stream>>>(bufA, adj, rowptr, dinv, cnt, b2, bufB, N);
    // hl = h2 @ Wl + bl
    gemm_rk<32, 128, 4><<<CDIV(N, 64), 256, 0, stream>>>(bufB, Wl, bl, hl, N);
    // rs aggregation (mean by cnt)
    agg_rs_k<<<CDIV(N, 8), 256, 0, stream>>>(hl, adj, rowptr, cnt, bufA, N);
    // graph mean + head
    graph_sum_k<<<CDIV(N, 1024), 256, 0, stream>>>(bufA, batch, gsum, N);
    mlp_k<<<1, 256, 0, stream>>>(gsum, gcnt, Wm1, bm1, Wm2, bm2, (float*)d_out, Gn);
}

// Round 10
// 399.254 us; speedup vs baseline: 1.7287x; 1.0677x over previous
//
#include <hip/hip_runtime.h>
#include <hip/hip_bf16.h>
#include <stdint.h>

#define CDIV(a, b) (((a) + (b) - 1) / (b))

// Bucketed CSR build: bucket = tgt >> BSH (512 nodes / bucket).
constexpr int BSH = 9;
#define TILE_A 2048

__global__ __launch_bounds__(256) void coarse_hist_k(const int* __restrict__ tgt,
                                                     int* __restrict__ bcnt, int E, int nb) {
    __shared__ int h[512];
    int t = threadIdx.x;
    for (int i = t; i < nb; i += 256) h[i] = 0;
    __syncthreads();
    for (int e = blockIdx.x * 256 + t; e < E; e += gridDim.x * 256)
        atomicAdd(&h[tgt[e] >> BSH], 1);
    __syncthreads();
    for (int i = t; i < nb; i += 256)
        if (h[i]) atomicAdd(&bcnt[i], h[i]);
}

__global__ __launch_bounds__(256) void bucket_scan_k(const int* __restrict__ bcnt,
                                                     int* __restrict__ bbase,
                                                     int* __restrict__ bcur, int nb, int E) {
    __shared__ int sp[256];
    int t = threadIdx.x;
    int c0 = (2 * t < nb) ? bcnt[2 * t] : 0;
    int c1 = (2 * t + 1 < nb) ? bcnt[2 * t + 1] : 0;
    int s2 = c0 + c1;
    sp[t] = s2;
    __syncthreads();
    for (int off = 1; off < 256; off <<= 1) {
        int x = (t >= off) ? sp[t - off] : 0;
        __syncthreads();
        sp[t] += x;
        __syncthreads();
    }
    int excl = sp[t] - s2;
    if (2 * t < nb) { bbase[2 * t] = excl; bcur[2 * t] = excl; }
    if (2 * t + 1 < nb) { bbase[2 * t + 1] = excl + c0; bcur[2 * t + 1] = excl + c0; }
    if (t == 0) bbase[nb] = E;
}

__global__ __launch_bounds__(256) void binA_k(const int* __restrict__ ei,
                                              const int* __restrict__ ea,
                                              int* __restrict__ bcur,
                                              unsigned long long* __restrict__ tmp, int E) {
    __shared__ unsigned long long stage[TILE_A];
    __shared__ int h_cnt[512], h_excl[512], h_cur[512], h_run[512], sp[256];
    int t = threadIdx.x;
    int base = blockIdx.x * TILE_A;
    int nt = min(TILE_A, E - base);
    for (int i = t; i < 512; i += 256) { h_cnt[i] = 0; h_cur[i] = 0; }
    __syncthreads();
    unsigned long long pk[8];
    int bk[8];
#pragma unroll
    for (int k = 0; k < 8; ++k) {
        int e = base + t + k * 256;
        bk[k] = -1;
        if (e < E) {
            int s = ei[e], tg = ei[E + e];
            unsigned a = (unsigned)ea[e];
            pk[k] = ((unsigned long long)(unsigned)tg << 20) |
                    ((unsigned long long)a << 18) | (unsigned long long)(unsigned)s;
            bk[k] = tg >> BSH;
            atomicAdd(&h_cnt[bk[k]], 1);
        }
    }
    __syncthreads();
    int c0 = h_cnt[2 * t], c1 = h_cnt[2 * t + 1];
    int s2 = c0 + c1;
    sp[t] = s2;
    __syncthreads();
    for (int off = 1; off < 256; off <<= 1) {
        int x = (t >= off) ? sp[t - off] : 0;
        __syncthreads();
        sp[t] += x;
        __syncthreads();
    }
    int excl = sp[t] - s2;
    h_excl[2 * t] = excl;
    h_excl[2 * t + 1] = excl + c0;
    __syncthreads();
    for (int i = t; i < 512; i += 256)
        if (h_cnt[i]) h_run[i] = atomicAdd(&bcur[i], h_cnt[i]);
#pragma unroll
    for (int k = 0; k < 8; ++k) {
        if (bk[k] >= 0) {
            int r = atomicAdd(&h_cur[bk[k]], 1);
            stage[h_excl[bk[k]] + r] = pk[k];
        }
    }
    __syncthreads();
    for (int i = t; i < nt; i += 256) {
        unsigned long long v = stage[i];
        int b = (int)(v >> 20) >> BSH;
        tmp[h_run[b] + (i - h_excl[b])] = v;
    }
}

__global__ __launch_bounds__(256) void binB_k(const unsigned long long* __restrict__ tmp,
                                              const int* __restrict__ bbase,
                                              unsigned* __restrict__ adj,
                                              int* __restrict__ rowptr,
                                              int* __restrict__ cnt,
                                              float* __restrict__ dinv, int N, int E) {
    __shared__ int ncnt[512], nbase[512], ncur[512], sp[256];
    int t = threadIdx.x, b = blockIdx.x;
    int e0 = bbase[b], e1 = bbase[b + 1];
    int node0 = b << BSH;
    int nn = min(512, N - node0);
    for (int i = t; i < 512; i += 256) { ncnt[i] = 0; ncur[i] = 0; }
    __syncthreads();
    for (int e = e0 + t; e < e1; e += 256) {
        int li = (int)(tmp[e] >> 20) - node0;
        atomicAdd(&ncnt[li], 1);
    }
    __syncthreads();
    int c0 = ncnt[2 * t], c1 = ncnt[2 * t + 1];
    int s2 = c0 + c1;
    sp[t] = s2;
    __syncthreads();
    for (int off = 1; off < 256; off <<= 1) {
        int x = (t >= off) ? sp[t - off] : 0;
        __syncthreads();
        sp[t] += x;
        __syncthreads();
    }
    int excl = sp[t] - s2;
    nbase[2 * t] = excl;
    nbase[2 * t + 1] = excl + c0;
    __syncthreads();
    for (int i = t; i < nn; i += 256) {
        int node = node0 + i;
        rowptr[node] = e0 + nbase[i];
        int c = ncnt[i];
        cnt[node] = c;
        dinv[node] = rsqrtf((float)c + 1.0f);
    }
    if (b == 0 && t == 0) rowptr[N] = E;
    for (int e = e0 + t; e < e1; e += 256) {
        unsigned long long v = tmp[e];
        int li = (int)(v >> 20) - node0;
        int r = atomicAdd(&ncur[li], 1);
        adj[e0 + nbase[li] + r] = (unsigned)(v & 0xFFFFFull);
    }
}

// batch sorted: gcnt via binary search, no atomics
__device__ __forceinline__ int lb_sorted(const int* __restrict__ b, int n, int g) {
    int lo = 0, hi = n;
    while (lo < hi) {
        int m = (lo + hi) >> 1;
        if (b[m] < g) lo = m + 1; else hi = m;
    }
    return lo;
}

__global__ __launch_bounds__(256) void gbounds_k(const int* __restrict__ batch,
                                                 int* __restrict__ gcnt, int n, int Gn) {
    int g = blockIdx.x * 256 + threadIdx.x;
    if (g < Gn) {
        int a = lb_sorted(batch, n, g);
        int b2 = lb_sorted(batch, n, g + 1);
        gcnt[g] = b2 - a;
    }
}

// ---------------- GEMM: Y[n,COUT] = X[n,K] @ W[K,COUT] (+bias) ----------------
template <int K, int COUT, int R>
__global__ __launch_bounds__(256) void gemm_rk(const float* __restrict__ X,
                                               const float* __restrict__ W,
                                               const float* __restrict__ bias,
                                               float* __restrict__ Y, int nrows) {
    constexpr int NCG = COUT / 8;
    constexpr int RG = 256 / NCG;
    constexpr int ROWS = RG * R;
    constexpr int WS = K + 4;
    __shared__ float wt[COUT][WS];
    int t = threadIdx.x;
    for (int i = t; i < K * COUT; i += 256) {
        int k = i / COUT, j = i % COUT;
        wt[j][k] = W[i];
    }
    __syncthreads();
    int cg = t % NCG, g = t / NCG;
    int j0 = cg * 8;
    long rowbase = (long)blockIdx.x * ROWS + (long)g * R;
    float acc[R][8];
#pragma unroll
    for (int r = 0; r < R; ++r)
#pragma unroll
        for (int j = 0; j < 8; ++j) acc[r][j] = 0.0f;

    long rr[R];
#pragma unroll
    for (int r = 0; r < R; ++r) {
        long q = rowbase + r;
        rr[r] = (q < nrows) ? q : (long)(nrows - 1);
    }
    for (int k0 = 0; k0 < K; k0 += 4) {
        float4 xv[R];
#pragma unroll
        for (int r = 0; r < R; ++r) xv[r] = *(const float4*)(X + rr[r] * K + k0);
        float4 wv[8];
#pragma unroll
        for (int j = 0; j < 8; ++j) wv[j] = *(const float4*)&wt[j0 + j][k0];
#pragma unroll
        for (int r = 0; r < R; ++r)
#pragma unroll
            for (int j = 0; j < 8; ++j) {
                acc[r][j] += xv[r].x * wv[j].x;
                acc[r][j] += xv[r].y * wv[j].y;
                acc[r][j] += xv[r].z * wv[j].z;
                acc[r][j] += xv[r].w * wv[j].w;
            }
    }
#pragma unroll
    for (int r = 0; r < R; ++r) {
        long row = rowbase + r;
        if (row < nrows) {
            float o[8];
#pragma unroll
            for (int j = 0; j < 8; ++j) {
                float v = acc[r][j];
                if (bias) v += bias[j0 + j];
                o[j] = v;
            }
            float4 o0 = make_float4(o[0], o[1], o[2], o[3]);
            float4 o1 = make_float4(o[4], o[5], o[6], o[7]);
            *(float4*)&Y[row * COUT + j0] = o0;
            *(float4*)&Y[row * COUT + j0 + 4] = o1;
        }
    }
}

// ---------------- GCN edge aggregation (gather over CSR) ----------------

__global__ __launch_bounds__(256) void agg_conv_k(const float* __restrict__ xw,
                                                  const unsigned* __restrict__ adj,
                                                  const int* __restrict__ rowptr,
                                                  const float* __restrict__ dinv,
                                                  const int* __restrict__ cnt,
                                                  const float* __restrict__ bias,
                                                  float* __restrict__ out, int n) {
    int t = threadIdx.x;
    int node = blockIdx.x * 8 + (t >> 5);
    int f = t & 31;
    if (node >= n) return;
    int e0 = rowptr[node], e1 = rowptr[node + 1];
    float a0 = 0.0f, a1 = 0.0f;
    int e = e0;
    for (; e + 1 < e1; e += 2) {
        unsigned u0 = adj[e], u1 = adj[e + 1];
        int s0 = u0 & 0x3FFFF, s1 = u1 & 0x3FFFF;
        a0 += dinv[s0] * xw[s0 * 32 + f];
        a1 += dinv[s1] * xw[s1 * 32 + f];
    }
    if (e < e1) {
        unsigned u = adj[e];
        int s = u & 0x3FFFF;
        a0 += dinv[s] * xw[s * 32 + f];
    }
    float degv = (float)cnt[node] + 1.0f;
    float v = dinv[node] * (a0 + a1) + xw[node * 32 + f] * (1.0f / degv) + bias[f];
    out[node * 32 + f] = fmaxf(v, 0.0f);
}

// ---------------- fused rs aggregation: agg = (A_q @ Wl_q + m_q*bl_q)/cnt ----------------
// Exploits linearity: hl = h2 @ Wl + bl never materialized. Gather h2 (L2-resident),
// accumulate per-attr sums A_q in registers, per-node 128->32 epilogue with LDS Wl.
__global__ __launch_bounds__(256) void agg_rs_fused_k(const float* __restrict__ h2,
                                                      const unsigned* __restrict__ adj,
                                                      const int* __restrict__ rowptr,
                                                      const int* __restrict__ cnt,
                                                      const float* __restrict__ Wl,
                                                      const float* __restrict__ bl,
                                                      float* __restrict__ out, int n) {
    __shared__ float wls[32][128];   // Wl[j][c], 16 KB
    __shared__ float bls[128];
    __shared__ float accs[8][128];   // per-node A_q staging, 4 KB
    int t = threadIdx.x;
    for (int i = t; i < 4096; i += 256) wls[i >> 7][i & 127] = Wl[i];
    if (t < 128) bls[t] = bl[t];
    __syncthreads();

    int nl = t >> 5;
    int f = t & 31;
    int node = blockIdx.x * 8 + nl;
    bool act = node < n;
    int e0 = 0, e1 = 0, c = 0;
    if (act) { e0 = rowptr[node]; e1 = rowptr[node + 1]; c = cnt[node]; }
    float a0 = 0.f, a1 = 0.f, a2 = 0.f, a3 = 0.f;
    int m0 = 0, m1 = 0, m2 = 0, m3 = 0;
    int e = e0;
    for (; e + 1 < e1; e += 2) {
        unsigned u0 = adj[e], u1 = adj[e + 1];
        int s0 = u0 & 0x3FFFF, s1 = u1 & 0x3FFFF;
        int q0 = u0 >> 18, q1 = u1 >> 18;
        float v0 = h2[s0 * 32 + f], v1 = h2[s1 * 32 + f];
        a0 += (q0 == 0) ? v0 : 0.f; m0 += (q0 == 0);
        a1 += (q0 == 1) ? v0 : 0.f; m1 += (q0 == 1);
        a2 += (q0 == 2) ? v0 : 0.f; m2 += (q0 == 2);
        a3 += (q0 == 3) ? v0 : 0.f; m3 += (q0 == 3);
        a0 += (q1 == 0) ? v1 : 0.f; m0 += (q1 == 0);
        a1 += (q1 == 1) ? v1 : 0.f; m1 += (q1 == 1);
        a2 += (q1 == 2) ? v1 : 0.f; m2 += (q1 == 2);
        a3 += (q1 == 3) ? v1 : 0.f; m3 += (q1 == 3);
    }
    if (e < e1) {
        unsigned u = adj[e];
        int s = u & 0x3FFFF;
        int q = u >> 18;
        float v = h2[s * 32 + f];
        a0 += (q == 0) ? v : 0.f; m0 += (q == 0);
        a1 += (q == 1) ? v : 0.f; m1 += (q == 1);
        a2 += (q == 2) ? v : 0.f; m2 += (q == 2);
        a3 += (q == 3) ? v : 0.f; m3 += (q == 3);
    }
    accs[nl][f] = a0;
    accs[nl][32 + f] = a1;
    accs[nl][64 + f] = a2;
    accs[nl][96 + f] = a3;
    __syncthreads();
    if (act) {
        float o = (float)m0 * bls[f] + (float)m1 * bls[32 + f] +
                  (float)m2 * bls[64 + f] + (float)m3 * bls[96 + f];
#pragma unroll 8
        for (int j = 0; j < 32; ++j) {
            float h0 = accs[nl][j], h1v = accs[nl][32 + j];
            float h2v = accs[nl][64 + j], h3 = accs[nl][96 + j];
            o += h0 * wls[j][f] + h1v * wls[j][32 + f] +
                 h2v * wls[j][64 + f] + h3 * wls[j][96 + f];
        }
        out[node * 32 + f] = o / fmaxf((float)c, 1.0f);
    }
}

// ---------------- graph pooling (batch sorted: boundary-atomic trick) ----------------

__global__ __launch_bounds__(256) void graph_sum_k(const float* __restrict__ agg,
                                                   const int* __restrict__ batch,
                                                   float* __restrict__ gsum, int n) {
    const int CHUNK = 128;
    int t = threadIdx.x;
    int f = t & 31;
    int j = t >> 5;
    long base = (long)blockIdx.x * (8 * CHUNK) + (long)j * CHUNK;
    if (base >= n) return;
    int end = (int)((n - base < CHUNK) ? (n - base) : CHUNK);
    int cur = batch[base];
    float acc = 0.0f;
    for (int i = 0; i < end; ++i) {
        int b = batch[base + i];
        if (b != cur) {
            atomicAdd(&gsum[cur * 32 + f], acc);
            acc = 0.0f;
            cur = b;
        }
        acc += agg[(base + i) * 32 + f];
    }
    atomicAdd(&gsum[cur * 32 + f], acc);
}

// ---------------- final MLP head ----------------

__global__ __launch_bounds__(256) void mlp_k(const float* __restrict__ gsum,
                                             const int* __restrict__ gcnt,
                                             const float* __restrict__ Wm1,
                                             const float* __restrict__ bm1,
                                             const float* __restrict__ Wm2,
                                             const float* __restrict__ bm2,
                                             float* __restrict__ out, int Gn) {
    __shared__ float w1[1024];
    __shared__ float w2[32];
    __shared__ float b1s[32];
    int t = threadIdx.x;
    for (int i = t; i < 1024; i += 256) w1[i] = Wm1[i];
    if (t < 32) {
        w2[t] = Wm2[t];
        b1s[t] = bm1[t];
    }
    __syncthreads();
    if (t < Gn) {
        float inv = 1.0f / fmaxf((float)gcnt[t], 1.0f);
        float gm[32];
#pragma unroll
        for (int k = 0; k < 32; ++k) gm[k] = gsum[t * 32 + k] * inv;
        float o = bm2[0];
        for (int j = 0; j < 32; ++j) {
            float h = b1s[j];
#pragma unroll
            for (int k = 0; k < 32; ++k) h += gm[k] * w1[k * 32 + j];
            o += fmaxf(h, 0.0f) * w2[j];
        }
        out[t] = 1.0f / (1.0f + expf(-o));
    }
}

// ---------------- launch ----------------

extern "C" void kernel_launch(void* const* d_in, const int* in_sizes, int n_in,
                              void* d_out, int out_size, void* d_ws, size_t ws_size,
                              hipStream_t stream) {
    const float* x = (const float*)d_in[0];
    const int* ei = (const int*)d_in[1];
    const int* ea = (const int*)d_in[2];
    const int* batch = (const int*)d_in[3];
    const float* W1 = (const float*)d_in[4];
    const float* b1 = (const float*)d_in[5];
    const float* W2 = (const float*)d_in[6];
    const float* b2 = (const float*)d_in[7];
    const float* Wl = (const float*)d_in[8];
    const float* bl = (const float*)d_in[9];
    const float* Wm1 = (const float*)d_in[10];
    const float* bm1 = (const float*)d_in[11];
    const float* Wm2 = (const float*)d_in[12];
    const float* bm2 = (const float*)d_in[13];

    const int N = in_sizes[3];
    const int E = in_sizes[2];
    const int Gn = out_size;
    const int NBUCKET = CDIV(N, 512);

    char* ws = (char*)d_ws;
    size_t off = 0;
    auto alloc = [&](size_t bytes) -> void* {
        void* p = ws + off;
        off = (off + bytes + 255) & ~(size_t)255;
        return p;
    };
    int* cnt = (int*)alloc((size_t)N * 4);
    int* rowptr = (int*)alloc((size_t)(N + 1) * 4);
    float* dinv = (float*)alloc((size_t)N * 4);
    int* bcnt = (int*)alloc(512 * 4);
    int* bbase = (int*)alloc(513 * 4);
    int* bcur = (int*)alloc(512 * 4);
    unsigned* adj = (unsigned*)alloc((size_t)E * 4);
    float* gsum = (float*)alloc((size_t)Gn * 32 * 4);
    int* gcnt = (int*)alloc((size_t)Gn * 4);
    float* bufA = (float*)alloc((size_t)N * 32 * 4);
    float* bufB = (float*)alloc((size_t)N * 32 * 4);
    unsigned long long* tmp = (unsigned long long*)alloc((size_t)E * 8);

    // Workspace / bucket-capacity guard (output stays zero -> absmax ~0.5 signature).
    if (off > ws_size || NBUCKET > 512) return;

    hipMemsetAsync(bcnt, 0, 512 * 4, stream);
    hipMemsetAsync(gsum, 0, (size_t)Gn * 32 * 4, stream);

    coarse_hist_k<<<400, 256, 0, stream>>>(ei + E, bcnt, E, NBUCKET);
    bucket_scan_k<<<1, 256, 0, stream>>>(bcnt, bbase, bcur, NBUCKET, E);
    binA_k<<<CDIV(E, TILE_A), 256, 0, stream>>>(ei, ea, bcur, tmp, E);
    binB_k<<<NBUCKET, 256, 0, stream>>>(tmp, bbase, adj, rowptr, cnt, dinv, N, E);
    gbounds_k<<<CDIV(Gn, 256), 256, 0, stream>>>(batch, gcnt, N, Gn);

    // conv1
    gemm_rk<128, 32, 4><<<CDIV(N, 256), 256, 0, stream>>>(x, W1, nullptr, bufA, N);
    agg_conv_k<<<CDIV(N, 8), 256, 0, stream>>>(bufA, adj, rowptr, dinv, cnt, b1, bufB, N);
    // conv2
    gemm_rk<32, 32, 4><<<CDIV(N, 256), 256, 0, stream>>>(bufB, W2, nullptr, bufA, N);
    agg_conv_k<<<CDIV(N, 8), 256, 0, stream>>>(bufA, adj, rowptr, dinv, cnt, b2, bufB, N);
    // fused: agg_rs without materializing hl = h2 @ Wl
    agg_rs_fused_k<<<CDIV(N, 8), 256, 0, stream>>>(bufB, adj, rowptr, cnt, Wl, bl, bufA, N);
    // graph mean + head
    graph_sum_k<<<CDIV(N, 1024), 256, 0, stream>>>(bufA, batch, gsum, N);
    mlp_k<<<1, 256, 0, stream>>>(gsum, gcnt, Wm1, bm1, Wm2, bm2, (float*)d_out, Gn);
}